// Round 9
// baseline (232.202 us; speedup 1.0000x reference)
//
#include <hip/hip_runtime.h>
#include <math.h>

typedef __bf16 bf16_t;
typedef __bf16 bf16x8 __attribute__((ext_vector_type(8)));
typedef float f32x4 __attribute__((ext_vector_type(4)));
typedef float f32x2 __attribute__((ext_vector_type(2)));

#define B_INS 8192
#define N_INS 16384
#define D 128
#define BP 256
#define P 256
#define NP 512

// exp(l-10) with l = dot*10  ==  exp2(dot*C1 - C1), C1 = 10*log2(e)
#define C1_CONST 14.426950408889634f

// ---------------- workspace layout (floats) ----------------
// acc[0]=ins sum, acc[1]=patch sum, acc[2]=n_valid, acc[3]=ticket
#define WS_ACC 0
#define WS_S 8
#define WS_POS (8 + 16384)
#define WS_SP (8 + 2 * 16384)
#define WS_PP (WS_SP + BP * NP)
#define WS_ZERO_FLOATS (WS_PP + BP * NP)        // 294920 floats = 73730 float4
#define EMB_I_BYTE ((((WS_ZERO_FLOATS) * 4 + 15) / 16) * 16)
#define EMB_P_BYTE (EMB_I_BYTE + N_INS * D * 2)

// Panel layout: row i, k -> panel p=i>>7, r=i&127, g=k>>3, j=k&7
// elem offset = (p<<14) + (g<<10) + (r<<3) + j. Panel = 32 KB contiguous.
// Half-panel (64 rows) staged compactly: g*512 + r*8 elems (16 KB).

// grid partitioning
#define NB_NORMI 256        // ins norm: 64 rows/block, single pass
#define NB_NORMP 2048
#define NB_ZERO 289
#define NB_PREP (NB_NORMI + NB_NORMP + NB_ZERO)
#define NB_INS 1088         // (R, chunk of 16 half-tiles), octet decode
#define NB_PATCHB 1024      // (batch, R-panel), C64 = 2R..7
#define NB_GRAM (NB_INS + NB_PATCHB)
#define NB_FIN 576          // 64 ins + 512 patch

// ---------------- staging: 16 KB half-panel copy (async, wave-uniform dst) ---
__device__ __forceinline__ void load_lds16(const bf16_t* g, bf16_t* l) {
    __builtin_amdgcn_global_load_lds(
        (const __attribute__((address_space(1))) void*)g,
        (__attribute__((address_space(3))) void*)l, 16, 0, 0);
}

// panel = 128-row panel base; c0loc = 0 or 64 (column half within panel).
// dst layout: g*512 + r*8 elems, r in [0,64).
__device__ __forceinline__ void stage_half(const bf16_t* __restrict__ panel,
                                           int c0loc, bf16_t* dst, int w, int lane) {
    const bf16_t* g = panel + ((c0loc + lane) << 3);
#pragma unroll
    for (int it = 0; it < 4; it++) {
        int gi = w * 4 + it;
        load_lds16(g + (gi << 10), dst + (gi << 9));
    }
}

// ---------------- A-fragment register load (from L2, panel layout) -----------
__device__ __forceinline__ void load_afrags(const bf16_t* __restrict__ abase,
                                            int rh, int tx, int q, bf16x8 af[4][4]) {
    const bf16_t* a = abase + ((rh * 64 + tx) << 3);
#pragma unroll
    for (int rt = 0; rt < 4; rt++)
#pragma unroll
        for (int ks = 0; ks < 4; ks++)
            af[rt][ks] = *(const bf16x8*)(a + (((ks << 2) + q) << 10) + (rt << 7));
}

// ================= kernel 1: prep (norms + workspace zero) =================
__global__ __launch_bounds__(256) void prep_k(const float* __restrict__ v1i,
                                              const float* __restrict__ v2i,
                                              const float* __restrict__ v1p,
                                              const float* __restrict__ v2p,
                                              bf16_t* __restrict__ embI,
                                              bf16_t* __restrict__ embP,
                                              float* __restrict__ ws) {
    __shared__ float L[128][65];
    __shared__ float ps[4][64];
    __shared__ float invs[64];
    int bx = blockIdx.x;
    int t = threadIdx.x;
    if (bx < NB_NORMI) {
        // single-pass ins norm: 4 lanes per row, 32 floats each in regs
        int r = t >> 2, h = t & 3;
        int i = bx * 64 + r;
        const float* row = ((i < B_INS) ? (v1i + (size_t)i * D)
                                        : (v2i + (size_t)(i - B_INS) * D)) + h * 32;
        float4 f[8];
#pragma unroll
        for (int j = 0; j < 8; j++) f[j] = *(const float4*)(row + j * 4);
        float ss = 0.f;
#pragma unroll
        for (int j = 0; j < 8; j++)
            ss += f[j].x * f[j].x + f[j].y * f[j].y + f[j].z * f[j].z + f[j].w * f[j].w;
        ss += __shfl_xor(ss, 1, 64);
        ss += __shfl_xor(ss, 2, 64);
        float inv = 1.0f / fmaxf(sqrtf(ss), 1e-12f);
        int p = i >> 7, rl = i & 127;
#pragma unroll
        for (int j = 0; j < 4; j++) {
            float4 a = f[2 * j], b = f[2 * j + 1];
            bf16x8 v;
            v[0] = (bf16_t)(a.x * inv); v[1] = (bf16_t)(a.y * inv);
            v[2] = (bf16_t)(a.z * inv); v[3] = (bf16_t)(a.w * inv);
            v[4] = (bf16_t)(b.x * inv); v[5] = (bf16_t)(b.y * inv);
            v[6] = (bf16_t)(b.z * inv); v[7] = (bf16_t)(b.w * inv);
            *(bf16x8*)(embI + ((size_t)p << 14) + ((h * 4 + j) << 10) + (rl << 3)) = v;
        }
    } else if (bx < NB_NORMI + NB_NORMP) {
        int bx2 = bx - NB_NORMI;
        int b = bx2 >> 3, h = (bx2 >> 2) & 1, chunk = bx2 & 3;
        int i0 = chunk * 64;
        const float* src = ((h == 0) ? v1p : v2p) + (size_t)b * D * P;
#pragma unroll
        for (int it = 0; it < 8; it++) {
            int fi = it * 256 + t;
            int d = fi >> 4, c4 = fi & 15;
            float4 v = *(const float4*)(src + (size_t)d * P + i0 + c4 * 4);
            L[d][c4 * 4 + 0] = v.x;
            L[d][c4 * 4 + 1] = v.y;
            L[d][c4 * 4 + 2] = v.z;
            L[d][c4 * 4 + 3] = v.w;
        }
        __syncthreads();
        {
            int col = t & 63, part = t >> 6;
            float ss = 0.f;
#pragma unroll 8
            for (int d = part * 32; d < part * 32 + 32; d++) { float x = L[d][col]; ss += x * x; }
            ps[part][col] = ss;
        }
        __syncthreads();
        if (t < 64) {
            float n2 = ps[0][t] + ps[1][t] + ps[2][t] + ps[3][t];
            invs[t] = 1.0f / fmaxf(sqrtf(n2), 1e-12f);
        }
        __syncthreads();
#pragma unroll
        for (int it = 0; it < 4; it++) {
            int idx = it * 256 + t;
            int ic = idx & 63, g = idx >> 6;
            float inv = invs[ic];
            bf16x8 v;
#pragma unroll
            for (int j = 0; j < 8; j++) v[j] = (bf16_t)(L[g * 8 + j][ic] * inv);
            int iLoc = h * P + i0 + ic;
            *(bf16x8*)(embP + ((size_t)b << 16) + ((size_t)(iLoc >> 7) << 14) +
                       (g << 10) + ((iLoc & 127) << 3)) = v;
        }
    } else {
        int idx = (bx - NB_NORMI - NB_NORMP) * 256 + t;
        if (idx < WS_ZERO_FLOATS / 4)
            ((f32x4*)ws)[idx] = (f32x4){0.f, 0.f, 0.f, 0.f};
    }
}

// ================= kernel 2: unified Gram, 128x64 half-tiles, dbuf ==========
// Block = 4 waves: wave w -> rh = w&1 (64-row half), cq = w>>1 (32-col quarter).
// LDS dbuf 2 x 16 KB -> 4+ blocks/CU for latency hiding.
__global__ __launch_bounds__(256) void gram_k(const bf16_t* __restrict__ embI,
                                              const bf16_t* __restrict__ embP,
                                              float* __restrict__ S,
                                              float* __restrict__ pos,
                                              float* __restrict__ Sp,
                                              float* __restrict__ posp) {
    __shared__ __align__(16) bf16_t shB[2][8192];
    int t = threadIdx.x, w = t >> 6, lane = t & 63;
    int tx = lane & 15, q = lane >> 4;
    int rh = w & 1, cq = w >> 1;
    int bx = blockIdx.x;

    const bf16_t *Abase, *Bbase;
    float *Sarr, *posArr;
    int R, c0, n, diag0, pos0;
    if (bx < NB_INS) {
        // octet decode: R in octet k has 16-k chunks of 16 half-tiles
        int bid = bx, k = 0, cum = 0;
        while (bid >= cum + 8 * (16 - k)) { cum += 8 * (16 - k); k++; }
        int rem = bid - cum, cc = 16 - k;
        R = 8 * k + rem / cc;
        int ci = rem - (rem / cc) * cc;
        c0 = 2 * R + ci * 16;
        n = min(16, 256 - c0);
        Abase = embI + ((size_t)R << 14);
        Bbase = embI;
        Sarr = S; posArr = pos;
        diag0 = 2 * R; pos0 = 2 * R + 128;
    } else {
        int pi = bx - NB_INS;
        int b = pi >> 2; R = pi & 3;
        c0 = 2 * R; n = 8 - 2 * R;
        const bf16_t* base = embP + ((size_t)b << 16);
        Abase = base + ((size_t)R << 14);
        Bbase = base;
        Sarr = Sp + (size_t)b * NP; posArr = posp + (size_t)b * NP;
        diag0 = 2 * R; pos0 = 2 * R + 4;
    }
    int rowBase = R * 128;

    bf16x8 af[4][4];
    load_afrags(Abase, rh, tx, q, af);

    f32x2 rowS2[8];
#pragma unroll
    for (int i = 0; i < 8; i++) rowS2[i] = (f32x2){0.f, 0.f};

    stage_half(Bbase + ((size_t)(c0 >> 1) << 14), (c0 & 1) * 64, shB[0], w, lane);
    int cur = 0;
    for (int ti = 0; ti < n; ti++) {
        int C64 = c0 + ti;
        __syncthreads();   // drains vmcnt: buf[cur] staged; prior readers of buf[cur^1] done
        if (ti + 1 < n) {
            int nc = C64 + 1;
            stage_half(Bbase + ((size_t)(nc >> 1) << 14), (nc & 1) * 64,
                       shB[cur ^ 1], w, lane);
        }
        int h = C64 & 1;
        bool isDiag = ((C64 & ~1) == diag0);
        bool isPos = ((C64 & ~1) == pos0);
        int colBase = C64 * 64;
        const bf16_t* sb = shB[cur];

        float colS[2];
#pragma unroll
        for (int nt = 0; nt < 2; nt++) {
            int cloc = cq * 32 + nt * 16 + tx;
            bf16x8 bf[4];
#pragma unroll
            for (int ks = 0; ks < 4; ks++)
                bf[ks] = *(const bf16x8*)(sb + (((ks << 2) + q) << 9) + (cloc << 3));
            f32x4 acc[4];
#pragma unroll
            for (int rt = 0; rt < 4; rt++) acc[rt] = (f32x4){0.f, 0.f, 0.f, 0.f};
#pragma unroll
            for (int ks = 0; ks < 4; ks++)
#pragma unroll
                for (int rt = 0; rt < 4; rt++)
                    acc[rt] = __builtin_amdgcn_mfma_f32_16x16x32_bf16(
                        af[rt][ks], bf[ks], acc[rt], 0, 0, 0);

            f32x2 cs = (f32x2){0.f, 0.f};
#pragma unroll
            for (int rt = 0; rt < 4; rt++) {
                f32x2 l0 = {acc[rt][0], acc[rt][1]};
                f32x2 l1 = {acc[rt][2], acc[rt][3]};
                l0 = l0 * C1_CONST - C1_CONST;
                l1 = l1 * C1_CONST - C1_CONST;
                f32x2 e0 = {__builtin_amdgcn_exp2f(l0.x), __builtin_amdgcn_exp2f(l0.y)};
                f32x2 e1 = {__builtin_amdgcn_exp2f(l1.x), __builtin_amdgcn_exp2f(l1.y)};
                if (isDiag && rh == h) {
                    int inRow = rt * 16 + q * 4;   // row-local within rh half
                    if (inRow + 0 == cloc) e0.x = 0.f;
                    if (inRow + 1 == cloc) e0.y = 0.f;
                    if (inRow + 2 == cloc) e1.x = 0.f;
                    if (inRow + 3 == cloc) e1.y = 0.f;
                }
                rowS2[rt * 2] += e0;
                rowS2[rt * 2 + 1] += e1;
                cs += e0 + e1;
            }
            colS[nt] = cs.x + cs.y;

            if (isPos && rh == h) {
                int reg = tx - q * 4;
                if (reg >= 0 && reg < 4) {
                    int rt_m = cq * 2 + nt;
                    float pl = acc[rt_m][reg] * 10.0f;
                    atomicAdd(&posArr[rowBase + rh * 64 + rt_m * 16 + tx], pl);
                    atomicAdd(&posArr[colBase + cloc], pl);
                }
            }
        }
        if (!isDiag) {
#pragma unroll
            for (int i = 0; i < 2; i++) {
                colS[i] += __shfl_xor(colS[i], 16, 64);
                colS[i] += __shfl_xor(colS[i], 32, 64);
            }
            if (q == 0) {
#pragma unroll
                for (int nt = 0; nt < 2; nt++)
                    atomicAdd(&Sarr[colBase + cq * 32 + nt * 16 + tx], colS[nt]);
            }
        }
        cur ^= 1;
    }
    // flush rowS: reduce over 16 tx lanes, one atomic per row (partial per cq)
    float* rowS = (float*)rowS2;   // [rt*4 + reg]
#pragma unroll
    for (int off = 1; off <= 8; off <<= 1)
#pragma unroll
        for (int i = 0; i < 16; i++) rowS[i] += __shfl_xor(rowS[i], off, 16);
    if (tx == 0) {
#pragma unroll
        for (int rt = 0; rt < 4; rt++)
#pragma unroll
            for (int reg = 0; reg < 4; reg++)
                atomicAdd(&Sarr[rowBase + rh * 64 + rt * 16 + q * 4 + reg],
                          rowS[rt * 4 + reg]);
    }
}

// ================= kernel 3: finalize =================
__global__ __launch_bounds__(256) void fin_k(const float* __restrict__ S,
                                             const float* __restrict__ pos,
                                             const float* __restrict__ Sp,
                                             const float* __restrict__ posp,
                                             const int* __restrict__ c1,
                                             const int* __restrict__ c2,
                                             float* __restrict__ acc,
                                             float* __restrict__ out) {
    int bx = blockIdx.x, t = threadIdx.x;
    int lane = t & 63, w = t >> 6;
    float va = 0.f, nv = 0.f;
    if (bx < 64) {
        int i = bx * 256 + t;
        va = __logf(S[i]) + 10.0f - pos[i];
    } else {
        int idx = (bx - 64) * 256 + t;   // over BP*NP
        int b = idx >> 9, i = idx & 511;
        int cnt = (i < P) ? c1[b * P + i] : c2[b * P + i - P];
        bool valid = (cnt != 0);
        va = valid ? (__logf(Sp[idx]) + 10.0f - posp[idx]) : 0.f;
        nv = valid ? 1.0f : 0.0f;
    }
#pragma unroll
    for (int off = 32; off >= 1; off >>= 1) {
        va += __shfl_down(va, off, 64);
        nv += __shfl_down(nv, off, 64);
    }
    __shared__ float ps[4], pn[4];
    if (lane == 0) { ps[w] = va; pn[w] = nv; }
    __syncthreads();
    if (t == 0) {
        float sv = ps[0] + ps[1] + ps[2] + ps[3];
        float sn = pn[0] + pn[1] + pn[2] + pn[3];
        if (bx < 64) {
            atomicAdd(&acc[0], sv);
        } else {
            atomicAdd(&acc[1], sv);
            atomicAdd(&acc[2], sn);
        }
        __threadfence();
        unsigned old = atomicAdd((unsigned*)&acc[3], 1u);
        if (old == NB_FIN - 1) {
            float a0 = atomicAdd(&acc[0], 0.0f);
            float a1 = atomicAdd(&acc[1], 0.0f);
            float a2 = atomicAdd(&acc[2], 0.0f);
            out[0] = a0 * (1.0f / (float)N_INS) + a1 / a2;
        }
    }
}

// ---------------- launch ----------------
extern "C" void kernel_launch(void* const* d_in, const int* in_sizes, int n_in,
                              void* d_out, int out_size, void* d_ws, size_t ws_size,
                              hipStream_t stream) {
    const float* v1i = (const float*)d_in[0];
    const float* v2i = (const float*)d_in[1];
    const float* v1p = (const float*)d_in[2];
    const float* v2p = (const float*)d_in[3];
    const int* c1 = (const int*)d_in[4];
    const int* c2 = (const int*)d_in[5];
    float* ws = (float*)d_ws;
    float* out = (float*)d_out;
    bf16_t* embI = (bf16_t*)((char*)d_ws + EMB_I_BYTE);
    bf16_t* embP = (bf16_t*)((char*)d_ws + EMB_P_BYTE);

    prep_k<<<NB_PREP, 256, 0, stream>>>(v1i, v2i, v1p, v2p, embI, embP, ws);
    gram_k<<<NB_GRAM, 256, 0, stream>>>(embI, embP, ws + WS_S, ws + WS_POS,
                                        ws + WS_SP, ws + WS_PP);
    fin_k<<<NB_FIN, 256, 0, stream>>>(ws + WS_S, ws + WS_POS, ws + WS_SP,
                                      ws + WS_PP, c1, c2, ws + WS_ACC, out);
}